// Round 7
// baseline (199.710 us; speedup 1.0000x reference)
//
#include <hip/hip_runtime.h>
#include <math.h>

// ---------------------------------------------------------------------------
// AttentionLayer: out = softmax(mask(q k^T * scale)) @ v,  q/k/v = x@W + b
// B=4, T=2048, C=H=768.  bf16 MFMA (16x16x32), fp32 accumulate.
// R10 (this round), from R9 post-mortem (197.3 us; qkv 52.5 us ~= the
//     2-phase structure ceiling; R9's vt 2B-scatter -> LDS-coalesce was the
//     big lever).  Apply the SAME proven mechanism everywhere:
//   - qkv z<2 epilogue: LDS-coalesced q/k stores (16B/lane).
//   - s_gemm epilogue: LDS-coalesced fp16 S stores (16B/lane).
//   - o_gemm epilogue: LDS-coalesced fp32 out stores, two 64-row passes.
//   - cast_x + transpose_w merged into one prep kernel (one less boundary).
//   k-loops, grids, launch bounds, rowstat: identical to R9.
// ---------------------------------------------------------------------------

#define BB 4
#define TT 2048
#define CC 768

typedef __bf16 bf16_t;
typedef __bf16 bf16x8 __attribute__((ext_vector_type(8)));
typedef _Float16 half8 __attribute__((ext_vector_type(8)));
typedef float f32x4 __attribute__((ext_vector_type(4)));

// ---------------------------------------------------------------------------
// async global->LDS 16B copy (wave-uniform LDS base + lane*16 implicit)
// ---------------------------------------------------------------------------
__device__ __forceinline__ void async_load16(void* lds, const void* g) {
  __builtin_amdgcn_global_load_lds(
      (const __attribute__((address_space(1))) void*)g,
      (__attribute__((address_space(3))) void*)lds, 16, 0, 0);
}

// Chunk swizzle for a 128x32 bf16 tile stored as 4x16B chunks per 64B row.
__device__ __forceinline__ int swz4(int r) {
  return (r & 3) ^ ((r >> 2) & 3);
}

// Stage a 128x32 bf16 tile (row-major, row stride ld elements) into LDS.
__device__ __forceinline__ void stage_tile(const bf16_t* __restrict__ g0,
                                           int ld, bf16_t* lds, int t) {
  int w = t >> 6, l = t & 63;
#pragma unroll
  for (int i = 0; i < 2; ++i) {
    int c = i * 256 + w * 64 + l;   // linear 16B-chunk id in LDS
    int row = c >> 2;
    int p = c & 3;
    int q = p ^ swz4(row);          // logical chunk to fetch
    async_load16(lds + i * 2048 + w * 512,  // wave-uniform base (elements)
                 g0 + row * ld + q * 8);
  }
}

// Read one MFMA fragment (8 bf16, 16B) for logical (row r, k-chunk q).
__device__ __forceinline__ bf16x8 read_frag(const bf16_t* lds, int r, int q) {
  int p = q ^ swz4(r);
  return *(const bf16x8*)(lds + r * 32 + p * 8);
}

// One 128x128x32 MFMA step from a published LDS buffer pair.
__device__ __forceinline__ void mfma_tile(const bf16_t* Ab, const bf16_t* Bb,
                                          int wr, int wc, int l,
                                          f32x4 acc[4][4]) {
  bf16x8 af[4], bfr[4];
  int q = l >> 4;
#pragma unroll
  for (int i = 0; i < 4; ++i) {
    af[i] = read_frag(Ab, wr + i * 16 + (l & 15), q);
    bfr[i] = read_frag(Bb, wc + i * 16 + (l & 15), q);
  }
#pragma unroll
  for (int mi = 0; mi < 4; ++mi)
#pragma unroll
    for (int ni = 0; ni < 4; ++ni)
      acc[mi][ni] = __builtin_amdgcn_mfma_f32_16x16x32_bf16(
          af[mi], bfr[ni], acc[mi][ni], 0, 0, 0);
}

// Core: C[128x128] += A[128xK] * B^T.  kTiles must be EVEN.
// R3-proven unroll-2 static double-buffer; plain __syncthreads; 32 KB LDS.
__device__ __forceinline__ void gemm_core(const bf16_t* __restrict__ A, int lda,
                                          const bf16_t* __restrict__ B, int ldb,
                                          int kTiles, bf16_t* As0, bf16_t* As1,
                                          bf16_t* Bs0, bf16_t* Bs1,
                                          f32x4 acc[4][4]) {
  int t = threadIdx.x;
  int l = t & 63;
  int w = t >> 6;
  int wr = (w >> 1) * 64;  // wave row offset in 128-tile
  int wc = (w & 1) * 64;   // wave col offset

  stage_tile(A, lda, As0, t);  // k-tile 0 -> buf0
  stage_tile(B, ldb, Bs0, t);

  for (int kt = 0; kt < kTiles; kt += 2) {
    __syncthreads();  // publish buf0(kt); prior buf1 reads complete
    stage_tile(A + (kt + 1) * 32, lda, As1, t);   // prefetch kt+1
    stage_tile(B + (kt + 1) * 32, ldb, Bs1, t);
    mfma_tile(As0, Bs0, wr, wc, l, acc);
    __syncthreads();  // publish buf1(kt+1); buf0 reads complete
    if (kt + 2 < kTiles) {
      stage_tile(A + (kt + 2) * 32, lda, As0, t);  // prefetch kt+2
      stage_tile(B + (kt + 2) * 32, ldb, Bs0, t);
    }
    mfma_tile(As1, Bs1, wr, wc, l, acc);
  }
}

// C/D layout (m89-verified): col = lane&15, row = (lane>>4)*4 + reg.

// ---------------------------------------------------------------------------
// Kernel 1: prep = cast x (fp32->bf16, blocks [0,3072)) + transpose+cast the
// three weight matrices [C][H] -> bf16 [H][C] (blocks [3072,4800)).
// ---------------------------------------------------------------------------
__global__ __launch_bounds__(256) void prep_kernel(
    const float* __restrict__ x, const float* __restrict__ Wq,
    const float* __restrict__ Wk, const float* __restrict__ Wv,
    bf16_t* __restrict__ xbf, bf16_t* __restrict__ wt) {
  __shared__ float tile[32][33];
  int bid = blockIdx.x;
  int t = threadIdx.x;
  if (bid < 3072) {
    int i = bid * 256 + t;
    const float4* xin = (const float4*)x;
    float4 a = xin[i * 2];
    float4 b = xin[i * 2 + 1];
    bf16_t tmp[8];
    tmp[0] = (bf16_t)a.x; tmp[1] = (bf16_t)a.y;
    tmp[2] = (bf16_t)a.z; tmp[3] = (bf16_t)a.w;
    tmp[4] = (bf16_t)b.x; tmp[5] = (bf16_t)b.y;
    tmp[6] = (bf16_t)b.z; tmp[7] = (bf16_t)b.w;
    *(uint4*)(xbf + (size_t)i * 8) = *(const uint4*)tmp;
  } else {
    int r = bid - 3072;           // 0..1727 = 3 z * 576
    int z = r / 576;
    r -= z * 576;                 // 576 = 24*24
    int by = r / 24, bx = r - by * 24;
    const float* W = (z == 0) ? Wq : (z == 1) ? Wk : Wv;
    bf16_t* out = wt + (size_t)z * CC * CC;
    int tx = t & 31, ty = t >> 5;
    int n0 = bx * 32, c0 = by * 32;
#pragma unroll
    for (int k = 0; k < 4; ++k)
      tile[ty + k * 8][tx] = W[(size_t)(c0 + ty + k * 8) * CC + n0 + tx];
    __syncthreads();
#pragma unroll
    for (int k = 0; k < 4; ++k)
      out[(size_t)(n0 + ty + k * 8) * CC + c0 + tx] =
          (bf16_t)tile[tx][ty + k * 8];
  }
}

// ---------------------------------------------------------------------------
// Kernel 3: QKV GEMM, 1D grid of 1152 = 8 XCD chunks x 144.
// z=0: q (scaled by H^-1/2), z=1: k, z=2: v transposed.  ALL epilogues now
// LDS-coalesced (16B/lane stores).
// ---------------------------------------------------------------------------
__global__ __launch_bounds__(256) void qkv_gemm_kernel(
    const bf16_t* __restrict__ xbf, const bf16_t* __restrict__ wt,
    const float* __restrict__ bq, const float* __restrict__ bk,
    const float* __restrict__ bv, bf16_t* __restrict__ qb,
    bf16_t* __restrict__ kb, bf16_t* __restrict__ vt) {
  __shared__ bf16_t smem[16384];  // 32KB: gemm dbuf, then epilogue buf
  int bid = blockIdx.x;
  int work = (bid & 7) * 144 + (bid >> 3);  // 1152 = 8 * 144 (bijective)
  int z = work / 384;
  int rw = work - z * 384;
  int m0 = (rw / 6) * 128;
  int n0 = (rw % 6) * 128;

  f32x4 acc[4][4];
#pragma unroll
  for (int i = 0; i < 4; ++i)
#pragma unroll
    for (int j = 0; j < 4; ++j) acc[i][j] = (f32x4){0.f, 0.f, 0.f, 0.f};

  const bf16_t* A = xbf + (size_t)m0 * CC;
  const bf16_t* B = wt + (size_t)z * CC * CC + (size_t)n0 * CC;
  gemm_core(A, CC, B, CC, CC / 32, smem, smem + 4096, smem + 8192,
            smem + 12288, acc);

  int t = threadIdx.x;
  int l = t & 63, w = t >> 6;
  int wr = (w >> 1) * 64, wc = (w & 1) * 64;
  const float* bias = (z == 0) ? bq : (z == 1) ? bk : bv;
  __syncthreads();  // all waves done reading gemm LDS buffers

  if (z < 2) {
    float scale = (z == 0) ? rsqrtf((float)CC) : 1.0f;
    bf16_t* dst = (z == 0) ? qb : kb;
    // stage tile into LDS [row][col] bf16, 16B-chunk XOR by row&7
#pragma unroll
    for (int mi = 0; mi < 4; ++mi) {
#pragma unroll
      for (int ni = 0; ni < 4; ++ni) {
        int cl = wc + ni * 16 + (l & 15);
        int rb = wr + mi * 16 + (l >> 4) * 4;
        float bcol = bias[n0 + cl];
#pragma unroll
        for (int r = 0; r < 4; ++r) {
          int row = rb + r;
          float v = (acc[mi][ni][r] + bcol) * scale;
          smem[row * 128 + (((cl >> 3) ^ (row & 7)) << 3) + (cl & 7)] =
              (bf16_t)v;
        }
      }
    }
    __syncthreads();
#pragma unroll
    for (int g = 0; g < 8; ++g) {
      int row = g * 16 + (t >> 4);
      int ck = t & 15;
      uint4 v = *(const uint4*)(smem + row * 128 + ((ck ^ (row & 7)) << 3));
      *(uint4*)(dst + (size_t)(m0 + row) * CC + n0 + ck * 8) = v;
    }
  } else {
    // v^T: stage as [col][m] (chunk-XOR), write 16B/lane along T.
#pragma unroll
    for (int mi = 0; mi < 4; ++mi) {
#pragma unroll
      for (int ni = 0; ni < 4; ++ni) {
        int cl = wc + ni * 16 + (l & 15);
        int mlb = wr + mi * 16 + (l >> 4) * 4;
        float bcol = bias[n0 + cl];
        bf16_t t4[4];
#pragma unroll
        for (int r = 0; r < 4; ++r) t4[r] = (bf16_t)(acc[mi][ni][r] + bcol);
        int e = cl * 128 + (((mlb >> 3) ^ (cl & 15)) << 3) + (mlb & 7);
        *(uint2*)((unsigned int*)smem + (e >> 1)) = *(const uint2*)t4;
      }
    }
    __syncthreads();
    int b = m0 >> 11;
    int tt0 = m0 & (TT - 1);
#pragma unroll
    for (int g = 0; g < 8; ++g) {
      int cl = g * 16 + (t >> 4);
      int ck = t & 15;
      int phys = ck ^ (cl & 15);
      uint4 v = *(const uint4*)(smem + cl * 128 + phys * 8);
      *(uint4*)(vt + ((size_t)b * CC + n0 + cl) * TT + tt0 + ck * 8) = v;
    }
  }
}

// ---------------------------------------------------------------------------
// Kernel 4: S = q k^T, causal mask + (==0 -> -inf), fp16.  Live lower-tri
// grid (544 = 8 x 68).  LDS-coalesced S epilogue.
// ---------------------------------------------------------------------------
__global__ __launch_bounds__(256, 4) void s_gemm_kernel(
    const bf16_t* __restrict__ qb, const bf16_t* __restrict__ kb,
    _Float16* __restrict__ S) {
  __shared__ bf16_t smem[16384];
  int bid = blockIdx.x;
  int work = (bid & 7) * 68 + (bid >> 3);  // 544 = 8 * 68 (bijective)
  int b = work / 136;
  int t = work - b * 136;
  int ti = (int)((sqrtf(8.f * (float)t + 1.f) - 1.f) * 0.5f);
  while ((ti + 1) * (ti + 2) / 2 <= t) ++ti;  // guard fp rounding
  while (ti * (ti + 1) / 2 > t) --ti;
  int tj = t - ti * (ti + 1) / 2;
  int m0 = ti * 128, n0 = tj * 128;

  f32x4 acc[4][4];
#pragma unroll
  for (int i = 0; i < 4; ++i)
#pragma unroll
    for (int j = 0; j < 4; ++j) acc[i][j] = (f32x4){0.f, 0.f, 0.f, 0.f};

  const bf16_t* A = qb + ((size_t)b * TT + m0) * CC;
  const bf16_t* B = kb + ((size_t)b * TT + n0) * CC;
  gemm_core(A, CC, B, CC, CC / 32, smem, smem + 4096, smem + 8192,
            smem + 12288, acc);

  _Float16* Sb = S + (size_t)b * TT * TT;
  _Float16* lds = (_Float16*)smem;  // [128][128] fp16, chunk-XOR
  int tid = threadIdx.x;
  int l = tid & 63, w = tid >> 6;
  int wr = (w >> 1) * 64, wc = (w & 1) * 64;
  __syncthreads();
#pragma unroll
  for (int mi = 0; mi < 4; ++mi) {
#pragma unroll
    for (int ni = 0; ni < 4; ++ni) {
      int cl = wc + ni * 16 + (l & 15);
      int rb = wr + mi * 16 + (l >> 4) * 4;
      int j = n0 + cl;
#pragma unroll
      for (int r = 0; r < 4; ++r) {
        int row = rb + r;
        int i = m0 + row;
        float v = acc[mi][ni][r];
        if (j > i || v == 0.0f) v = -INFINITY;  // causal + reference quirk
        lds[row * 128 + (((cl >> 3) ^ (row & 7)) << 3) + (cl & 7)] =
            (_Float16)v;
      }
    }
  }
  __syncthreads();
#pragma unroll
  for (int g = 0; g < 8; ++g) {
    int row = g * 16 + (tid >> 4);
    int ck = tid & 15;
    uint4 v = *(const uint4*)(lds + row * 128 + ((ck ^ (row & 7)) << 3));
    *(uint4*)(Sb + (size_t)(m0 + row) * TT + n0 + ck * 8) = v;
  }
}

// ---------------------------------------------------------------------------
// Kernel 5: rowstat+normalize, wave-per-row (no LDS, no barriers).
// ---------------------------------------------------------------------------
__global__ __launch_bounds__(256) void rowstat_kernel(
    const _Float16* __restrict__ S, bf16_t* __restrict__ P) {
  int g = blockIdx.x * 4 + (threadIdx.x >> 6);  // global row id
  int b = g >> 11;
  int row = g & (TT - 1);
  int l = threadIdx.x & 63;
  const _Float16* s = S + ((size_t)b * TT + row) * TT;
  bf16_t* p = P + ((size_t)b * TT + row) * TT;
  int pe = ((row >> 7) + 1) << 7;  // padded causal length, multiple of 128

  float f[4][8];
#pragma unroll
  for (int c = 0; c < 4; ++c) {
    int j = (c * 64 + l) * 8;
    if (j < pe) {
      half8 h = *(const half8*)(s + j);
#pragma unroll
      for (int k = 0; k < 8; ++k) f[c][k] = (float)h[k];
    } else {
#pragma unroll
      for (int k = 0; k < 8; ++k) f[c][k] = -INFINITY;
    }
  }

  float m = f[0][0];
#pragma unroll
  for (int c = 0; c < 4; ++c)
#pragma unroll
    for (int k = 0; k < 8; ++k) m = fmaxf(m, f[c][k]);
#pragma unroll
  for (int off = 32; off > 0; off >>= 1) m = fmaxf(m, __shfl_xor(m, off));

  float e[4][8];
  float sum = 0.f;
#pragma unroll
  for (int c = 0; c < 4; ++c)
#pragma unroll
    for (int k = 0; k < 8; ++k) {
      e[c][k] = __expf(f[c][k] - m);  // exp(-inf)=0 for masked slots
      sum += e[c][k];
    }
#pragma unroll
  for (int off = 32; off > 0; off >>= 1) sum += __shfl_xor(sum, off);
  float inv = 1.0f / sum;

#pragma unroll
  for (int c = 0; c < 4; ++c) {
    int j = (c * 64 + l) * 8;
    if (j < pe) {
      bf16x8 o;
#pragma unroll
      for (int k = 0; k < 8; ++k) o[k] = (bf16_t)(e[c][k] * inv);
      *(bf16x8*)(p + j) = o;
    }
  }
}

// ---------------------------------------------------------------------------
// Kernel 6: O = P @ V.  Balance-paired 1D grid (384 = 8 x 48); K truncated
// at causal boundary.  LDS-coalesced fp32 epilogue, two 64-row passes.
// ---------------------------------------------------------------------------
__global__ __launch_bounds__(256, 4) void o_gemm_kernel(
    const bf16_t* __restrict__ P, const bf16_t* __restrict__ vt,
    float* __restrict__ out) {
  __shared__ bf16_t smem[16384];
  int bid = blockIdx.x;
  int work = (bid & 7) * 48 + (bid >> 3);  // 384 = 8 * 48 (bijective)
  int b = work / 96;
  int rw = work - b * 96;
  int i = rw / 6, nj = rw % 6;
  int ti = (i & 1) ? ((i - 1) >> 1) : (15 - (i >> 1));  // 15,0,14,1,...,8,7
  int m0 = ti * 128, n0 = nj * 128;

  f32x4 acc[4][4];
#pragma unroll
  for (int ii = 0; ii < 4; ++ii)
#pragma unroll
    for (int j = 0; j < 4; ++j) acc[ii][j] = (f32x4){0.f, 0.f, 0.f, 0.f};

  const bf16_t* A = P + ((size_t)b * TT + m0) * TT;
  const bf16_t* B = vt + ((size_t)b * CC + n0) * TT;
  gemm_core(A, TT, B, TT, (ti + 1) * 4, smem, smem + 4096, smem + 8192,
            smem + 12288, acc);

  float* Ob = out + (size_t)b * TT * CC;
  float* lds = (float*)smem;  // [64][128] f32, 4-f32-group XOR by row&7
  int tid = threadIdx.x;
  int l = tid & 63, w = tid >> 6;
  int wr = (w >> 1) * 64, wc = (w & 1) * 64;
#pragma unroll
  for (int h = 0; h < 2; ++h) {
    __syncthreads();
    if ((w >> 1) == h) {  // waves owning rows [h*64, h*64+64)
#pragma unroll
      for (int mi = 0; mi < 4; ++mi) {
#pragma unroll
        for (int ni = 0; ni < 4; ++ni) {
          int cl = wc + ni * 16 + (l & 15);
          int rb = mi * 16 + (l >> 4) * 4;  // 64-local row base
#pragma unroll
          for (int r = 0; r < 4; ++r) {
            int row = rb + r;
            lds[row * 128 + ((((cl >> 2) ^ (row & 7)) << 2) | (cl & 3))] =
                acc[mi][ni][r];
          }
        }
      }
    }
    __syncthreads();
#pragma unroll
    for (int g = 0; g < 8; ++g) {
      int row = g * 8 + (tid >> 5);  // 0..63
      int c = tid & 31;              // 16B chunk id
      uint4 v =
          *(const uint4*)(lds + row * 128 + ((c ^ (row & 7)) << 2));
      *(uint4*)(Ob + (size_t)(m0 + h * 64 + row) * CC + n0 + c * 4) = v;
    }
  }
}

// ---------------------------------------------------------------------------
extern "C" void kernel_launch(void* const* d_in, const int* in_sizes, int n_in,
                              void* d_out, int out_size, void* d_ws,
                              size_t ws_size, hipStream_t stream) {
  const float* x = (const float*)d_in[0];
  const float* Wq = (const float*)d_in[1];
  const float* bq = (const float*)d_in[2];
  const float* Wk = (const float*)d_in[3];
  const float* bk = (const float*)d_in[4];
  const float* Wv = (const float*)d_in[5];
  const float* bv = (const float*)d_in[6];
  float* out = (float*)d_out;

  char* ws = (char*)d_ws;
  size_t off = 0;
  auto carve = [&](size_t bytes) -> char* {
    char* p = ws + off;
    off += (bytes + 255) & ~(size_t)255;
    return p;
  };
  const size_t M = (size_t)BB * TT;  // 8192
  bf16_t* xbf = (bf16_t*)carve(M * CC * 2);            // 12.6 MB
  bf16_t* wt  = (bf16_t*)carve(3ull * CC * CC * 2);    // 3.5 MB
  bf16_t* qb  = (bf16_t*)carve(M * CC * 2);            // 12.6 MB
  bf16_t* kb  = (bf16_t*)carve(M * CC * 2);            // 12.6 MB
  bf16_t* vt  = (bf16_t*)carve(M * CC * 2);            // 12.6 MB (as [B][H][T])
  _Float16* S = (_Float16*)carve((size_t)BB * TT * TT * 2);  // 33.5 MB
  bf16_t* P   = (bf16_t*)carve((size_t)BB * TT * TT * 2);    // 33.5 MB
  (void)off; (void)ws_size;

  // 1: input prep (cast x + transpose W, one kernel)
  prep_kernel<<<4800, 256, 0, stream>>>(x, Wq, Wk, Wv, xbf, wt);
  // 3: q,k,v
  qkv_gemm_kernel<<<1152, 256, 0, stream>>>(xbf, wt, bq, bk, bv, qb, kb, vt);
  // 4: S = q k^T (lower-tri blocks, fp16)
  s_gemm_kernel<<<544, 256, 0, stream>>>(qb, kb, S);
  // 5: softmax rows -> P (bf16, zero-padded)
  rowstat_kernel<<<BB * TT / 4, 256, 0, stream>>>(S, P);
  // 6: O = P V
  o_gemm_kernel<<<384, 256, 0, stream>>>(P, vt, out);
}

// Round 8
// 199.058 us; speedup vs baseline: 1.0033x; 1.0033x over previous
//
#include <hip/hip_runtime.h>
#include <math.h>

// ---------------------------------------------------------------------------
// AttentionLayer: out = softmax(mask(q k^T * scale)) @ v,  q/k/v = x@W + b
// B=4, T=2048, C=H=768.  bf16 MFMA (16x16x32), fp32 accumulate.
// R11 (this round), from R10 post-mortem (199.7 us; qkv +2.9 us from the z<2
//     LDS epilogue -- q/k stores were already 32B-segment coalesced, so the
//     roundtrip cost > gain; s/o/prep changes netted -0.5):
//   - qkv z<2 epilogue REVERTED to R9 direct stores.  vt keeps the R9 LDS
//     path (its baseline was 2B stores at 4KB stride -- truly pathological).
//   - KEEP from R10: s_gemm/o_gemm LDS-coalesced epilogues, merged prep.
//   This is the union of best-measured per-kernel configs.
// ---------------------------------------------------------------------------

#define BB 4
#define TT 2048
#define CC 768

typedef __bf16 bf16_t;
typedef __bf16 bf16x8 __attribute__((ext_vector_type(8)));
typedef _Float16 half8 __attribute__((ext_vector_type(8)));
typedef float f32x4 __attribute__((ext_vector_type(4)));

// ---------------------------------------------------------------------------
// async global->LDS 16B copy (wave-uniform LDS base + lane*16 implicit)
// ---------------------------------------------------------------------------
__device__ __forceinline__ void async_load16(void* lds, const void* g) {
  __builtin_amdgcn_global_load_lds(
      (const __attribute__((address_space(1))) void*)g,
      (__attribute__((address_space(3))) void*)lds, 16, 0, 0);
}

// Chunk swizzle for a 128x32 bf16 tile stored as 4x16B chunks per 64B row.
__device__ __forceinline__ int swz4(int r) {
  return (r & 3) ^ ((r >> 2) & 3);
}

// Stage a 128x32 bf16 tile (row-major, row stride ld elements) into LDS.
__device__ __forceinline__ void stage_tile(const bf16_t* __restrict__ g0,
                                           int ld, bf16_t* lds, int t) {
  int w = t >> 6, l = t & 63;
#pragma unroll
  for (int i = 0; i < 2; ++i) {
    int c = i * 256 + w * 64 + l;   // linear 16B-chunk id in LDS
    int row = c >> 2;
    int p = c & 3;
    int q = p ^ swz4(row);          // logical chunk to fetch
    async_load16(lds + i * 2048 + w * 512,  // wave-uniform base (elements)
                 g0 + row * ld + q * 8);
  }
}

// Read one MFMA fragment (8 bf16, 16B) for logical (row r, k-chunk q).
__device__ __forceinline__ bf16x8 read_frag(const bf16_t* lds, int r, int q) {
  int p = q ^ swz4(r);
  return *(const bf16x8*)(lds + r * 32 + p * 8);
}

// One 128x128x32 MFMA step from a published LDS buffer pair.
__device__ __forceinline__ void mfma_tile(const bf16_t* Ab, const bf16_t* Bb,
                                          int wr, int wc, int l,
                                          f32x4 acc[4][4]) {
  bf16x8 af[4], bfr[4];
  int q = l >> 4;
#pragma unroll
  for (int i = 0; i < 4; ++i) {
    af[i] = read_frag(Ab, wr + i * 16 + (l & 15), q);
    bfr[i] = read_frag(Bb, wc + i * 16 + (l & 15), q);
  }
#pragma unroll
  for (int mi = 0; mi < 4; ++mi)
#pragma unroll
    for (int ni = 0; ni < 4; ++ni)
      acc[mi][ni] = __builtin_amdgcn_mfma_f32_16x16x32_bf16(
          af[mi], bfr[ni], acc[mi][ni], 0, 0, 0);
}

// Core: C[128x128] += A[128xK] * B^T.  kTiles must be EVEN.
// R3-proven unroll-2 static double-buffer; plain __syncthreads; 32 KB LDS.
__device__ __forceinline__ void gemm_core(const bf16_t* __restrict__ A, int lda,
                                          const bf16_t* __restrict__ B, int ldb,
                                          int kTiles, bf16_t* As0, bf16_t* As1,
                                          bf16_t* Bs0, bf16_t* Bs1,
                                          f32x4 acc[4][4]) {
  int t = threadIdx.x;
  int l = t & 63;
  int w = t >> 6;
  int wr = (w >> 1) * 64;  // wave row offset in 128-tile
  int wc = (w & 1) * 64;   // wave col offset

  stage_tile(A, lda, As0, t);  // k-tile 0 -> buf0
  stage_tile(B, ldb, Bs0, t);

  for (int kt = 0; kt < kTiles; kt += 2) {
    __syncthreads();  // publish buf0(kt); prior buf1 reads complete
    stage_tile(A + (kt + 1) * 32, lda, As1, t);   // prefetch kt+1
    stage_tile(B + (kt + 1) * 32, ldb, Bs1, t);
    mfma_tile(As0, Bs0, wr, wc, l, acc);
    __syncthreads();  // publish buf1(kt+1); buf0 reads complete
    if (kt + 2 < kTiles) {
      stage_tile(A + (kt + 2) * 32, lda, As0, t);  // prefetch kt+2
      stage_tile(B + (kt + 2) * 32, ldb, Bs0, t);
    }
    mfma_tile(As1, Bs1, wr, wc, l, acc);
  }
}

// C/D layout (m89-verified): col = lane&15, row = (lane>>4)*4 + reg.

// ---------------------------------------------------------------------------
// Kernel 1: prep = cast x (fp32->bf16, blocks [0,3072)) + transpose+cast the
// three weight matrices [C][H] -> bf16 [H][C] (blocks [3072,4800)).
// ---------------------------------------------------------------------------
__global__ __launch_bounds__(256) void prep_kernel(
    const float* __restrict__ x, const float* __restrict__ Wq,
    const float* __restrict__ Wk, const float* __restrict__ Wv,
    bf16_t* __restrict__ xbf, bf16_t* __restrict__ wt) {
  __shared__ float tile[32][33];
  int bid = blockIdx.x;
  int t = threadIdx.x;
  if (bid < 3072) {
    int i = bid * 256 + t;
    const float4* xin = (const float4*)x;
    float4 a = xin[i * 2];
    float4 b = xin[i * 2 + 1];
    bf16_t tmp[8];
    tmp[0] = (bf16_t)a.x; tmp[1] = (bf16_t)a.y;
    tmp[2] = (bf16_t)a.z; tmp[3] = (bf16_t)a.w;
    tmp[4] = (bf16_t)b.x; tmp[5] = (bf16_t)b.y;
    tmp[6] = (bf16_t)b.z; tmp[7] = (bf16_t)b.w;
    *(uint4*)(xbf + (size_t)i * 8) = *(const uint4*)tmp;
  } else {
    int r = bid - 3072;           // 0..1727 = 3 z * 576
    int z = r / 576;
    r -= z * 576;                 // 576 = 24*24
    int by = r / 24, bx = r - by * 24;
    const float* W = (z == 0) ? Wq : (z == 1) ? Wk : Wv;
    bf16_t* out = wt + (size_t)z * CC * CC;
    int tx = t & 31, ty = t >> 5;
    int n0 = bx * 32, c0 = by * 32;
#pragma unroll
    for (int k = 0; k < 4; ++k)
      tile[ty + k * 8][tx] = W[(size_t)(c0 + ty + k * 8) * CC + n0 + tx];
    __syncthreads();
#pragma unroll
    for (int k = 0; k < 4; ++k)
      out[(size_t)(n0 + ty + k * 8) * CC + c0 + tx] =
          (bf16_t)tile[tx][ty + k * 8];
  }
}

// ---------------------------------------------------------------------------
// Kernel 3: QKV GEMM, 1D grid of 1152 = 8 XCD chunks x 144.
// z=0: q (scaled by H^-1/2, direct stores), z=1: k (direct stores),
// z=2: v transposed (LDS-coalesced 16B stores).
// ---------------------------------------------------------------------------
__global__ __launch_bounds__(256) void qkv_gemm_kernel(
    const bf16_t* __restrict__ xbf, const bf16_t* __restrict__ wt,
    const float* __restrict__ bq, const float* __restrict__ bk,
    const float* __restrict__ bv, bf16_t* __restrict__ qb,
    bf16_t* __restrict__ kb, bf16_t* __restrict__ vt) {
  __shared__ bf16_t smem[16384];  // 32KB: gemm dbuf, then vt transpose buf
  int bid = blockIdx.x;
  int work = (bid & 7) * 144 + (bid >> 3);  // 1152 = 8 * 144 (bijective)
  int z = work / 384;
  int rw = work - z * 384;
  int m0 = (rw / 6) * 128;
  int n0 = (rw % 6) * 128;

  f32x4 acc[4][4];
#pragma unroll
  for (int i = 0; i < 4; ++i)
#pragma unroll
    for (int j = 0; j < 4; ++j) acc[i][j] = (f32x4){0.f, 0.f, 0.f, 0.f};

  const bf16_t* A = xbf + (size_t)m0 * CC;
  const bf16_t* B = wt + (size_t)z * CC * CC + (size_t)n0 * CC;
  gemm_core(A, CC, B, CC, CC / 32, smem, smem + 4096, smem + 8192,
            smem + 12288, acc);

  int t = threadIdx.x;
  int l = t & 63, w = t >> 6;
  int wr = (w >> 1) * 64, wc = (w & 1) * 64;
  const float* bias = (z == 0) ? bq : (z == 1) ? bk : bv;

  if (z < 2) {
    float scale = (z == 0) ? rsqrtf((float)CC) : 1.0f;
    bf16_t* dst = (z == 0) ? qb : kb;
#pragma unroll
    for (int mi = 0; mi < 4; ++mi) {
#pragma unroll
      for (int ni = 0; ni < 4; ++ni) {
        int col = n0 + wc + ni * 16 + (l & 15);
        int rbase = m0 + wr + mi * 16 + (l >> 4) * 4;
        float bcol = bias[col];
#pragma unroll
        for (int r = 0; r < 4; ++r) {
          float v = (acc[mi][ni][r] + bcol) * scale;
          dst[(size_t)(rbase + r) * CC + col] = (bf16_t)v;
        }
      }
    }
  } else {
    // v^T: stage as [col][m] (chunk-XOR), write 16B/lane along T.
    __syncthreads();  // all waves done reading gemm LDS buffers
#pragma unroll
    for (int mi = 0; mi < 4; ++mi) {
#pragma unroll
      for (int ni = 0; ni < 4; ++ni) {
        int cl = wc + ni * 16 + (l & 15);
        int mlb = wr + mi * 16 + (l >> 4) * 4;
        float bcol = bias[n0 + cl];
        bf16_t t4[4];
#pragma unroll
        for (int r = 0; r < 4; ++r) t4[r] = (bf16_t)(acc[mi][ni][r] + bcol);
        int e = cl * 128 + (((mlb >> 3) ^ (cl & 15)) << 3) + (mlb & 7);
        *(uint2*)((unsigned int*)smem + (e >> 1)) = *(const uint2*)t4;
      }
    }
    __syncthreads();
    int b = m0 >> 11;
    int tt0 = m0 & (TT - 1);
#pragma unroll
    for (int g = 0; g < 8; ++g) {
      int cl = g * 16 + (t >> 4);
      int ck = t & 15;
      int phys = ck ^ (cl & 15);
      uint4 v = *(const uint4*)(smem + cl * 128 + phys * 8);
      *(uint4*)(vt + ((size_t)b * CC + n0 + cl) * TT + tt0 + ck * 8) = v;
    }
  }
}

// ---------------------------------------------------------------------------
// Kernel 4: S = q k^T, causal mask + (==0 -> -inf), fp16.  Live lower-tri
// grid (544 = 8 x 68).  LDS-coalesced S epilogue.
// ---------------------------------------------------------------------------
__global__ __launch_bounds__(256, 4) void s_gemm_kernel(
    const bf16_t* __restrict__ qb, const bf16_t* __restrict__ kb,
    _Float16* __restrict__ S) {
  __shared__ bf16_t smem[16384];
  int bid = blockIdx.x;
  int work = (bid & 7) * 68 + (bid >> 3);  // 544 = 8 * 68 (bijective)
  int b = work / 136;
  int t = work - b * 136;
  int ti = (int)((sqrtf(8.f * (float)t + 1.f) - 1.f) * 0.5f);
  while ((ti + 1) * (ti + 2) / 2 <= t) ++ti;  // guard fp rounding
  while (ti * (ti + 1) / 2 > t) --ti;
  int tj = t - ti * (ti + 1) / 2;
  int m0 = ti * 128, n0 = tj * 128;

  f32x4 acc[4][4];
#pragma unroll
  for (int i = 0; i < 4; ++i)
#pragma unroll
    for (int j = 0; j < 4; ++j) acc[i][j] = (f32x4){0.f, 0.f, 0.f, 0.f};

  const bf16_t* A = qb + ((size_t)b * TT + m0) * CC;
  const bf16_t* B = kb + ((size_t)b * TT + n0) * CC;
  gemm_core(A, CC, B, CC, CC / 32, smem, smem + 4096, smem + 8192,
            smem + 12288, acc);

  _Float16* Sb = S + (size_t)b * TT * TT;
  _Float16* lds = (_Float16*)smem;  // [128][128] fp16, chunk-XOR
  int tid = threadIdx.x;
  int l = tid & 63, w = tid >> 6;
  int wr = (w >> 1) * 64, wc = (w & 1) * 64;
  __syncthreads();
#pragma unroll
  for (int mi = 0; mi < 4; ++mi) {
#pragma unroll
    for (int ni = 0; ni < 4; ++ni) {
      int cl = wc + ni * 16 + (l & 15);
      int rb = wr + mi * 16 + (l >> 4) * 4;
      int j = n0 + cl;
#pragma unroll
      for (int r = 0; r < 4; ++r) {
        int row = rb + r;
        int i = m0 + row;
        float v = acc[mi][ni][r];
        if (j > i || v == 0.0f) v = -INFINITY;  // causal + reference quirk
        lds[row * 128 + (((cl >> 3) ^ (row & 7)) << 3) + (cl & 7)] =
            (_Float16)v;
      }
    }
  }
  __syncthreads();
#pragma unroll
  for (int g = 0; g < 8; ++g) {
    int row = g * 16 + (tid >> 4);
    int ck = tid & 15;
    uint4 v = *(const uint4*)(lds + row * 128 + ((ck ^ (row & 7)) << 3));
    *(uint4*)(Sb + (size_t)(m0 + row) * TT + n0 + ck * 8) = v;
  }
}

// ---------------------------------------------------------------------------
// Kernel 5: rowstat+normalize, wave-per-row (no LDS, no barriers).
// ---------------------------------------------------------------------------
__global__ __launch_bounds__(256) void rowstat_kernel(
    const _Float16* __restrict__ S, bf16_t* __restrict__ P) {
  int g = blockIdx.x * 4 + (threadIdx.x >> 6);  // global row id
  int b = g >> 11;
  int row = g & (TT - 1);
  int l = threadIdx.x & 63;
  const _Float16* s = S + ((size_t)b * TT + row) * TT;
  bf16_t* p = P + ((size_t)b * TT + row) * TT;
  int pe = ((row >> 7) + 1) << 7;  // padded causal length, multiple of 128

  float f[4][8];
#pragma unroll
  for (int c = 0; c < 4; ++c) {
    int j = (c * 64 + l) * 8;
    if (j < pe) {
      half8 h = *(const half8*)(s + j);
#pragma unroll
      for (int k = 0; k < 8; ++k) f[c][k] = (float)h[k];
    } else {
#pragma unroll
      for (int k = 0; k < 8; ++k) f[c][k] = -INFINITY;
    }
  }

  float m = f[0][0];
#pragma unroll
  for (int c = 0; c < 4; ++c)
#pragma unroll
    for (int k = 0; k < 8; ++k) m = fmaxf(m, f[c][k]);
#pragma unroll
  for (int off = 32; off > 0; off >>= 1) m = fmaxf(m, __shfl_xor(m, off));

  float e[4][8];
  float sum = 0.f;
#pragma unroll
  for (int c = 0; c < 4; ++c)
#pragma unroll
    for (int k = 0; k < 8; ++k) {
      e[c][k] = __expf(f[c][k] - m);  // exp(-inf)=0 for masked slots
      sum += e[c][k];
    }
#pragma unroll
  for (int off = 32; off > 0; off >>= 1) sum += __shfl_xor(sum, off);
  float inv = 1.0f / sum;

#pragma unroll
  for (int c = 0; c < 4; ++c) {
    int j = (c * 64 + l) * 8;
    if (j < pe) {
      bf16x8 o;
#pragma unroll
      for (int k = 0; k < 8; ++k) o[k] = (bf16_t)(e[c][k] * inv);
      *(bf16x8*)(p + j) = o;
    }
  }
}

// ---------------------------------------------------------------------------
// Kernel 6: O = P @ V.  Balance-paired 1D grid (384 = 8 x 48); K truncated
// at causal boundary.  LDS-coalesced fp32 epilogue, two 64-row passes.
// ---------------------------------------------------------------------------
__global__ __launch_bounds__(256, 4) void o_gemm_kernel(
    const bf16_t* __restrict__ P, const bf16_t* __restrict__ vt,
    float* __restrict__ out) {
  __shared__ bf16_t smem[16384];
  int bid = blockIdx.x;
  int work = (bid & 7) * 48 + (bid >> 3);  // 384 = 8 * 48 (bijective)
  int b = work / 96;
  int rw = work - b * 96;
  int i = rw / 6, nj = rw % 6;
  int ti = (i & 1) ? ((i - 1) >> 1) : (15 - (i >> 1));  // 15,0,14,1,...,8,7
  int m0 = ti * 128, n0 = nj * 128;

  f32x4 acc[4][4];
#pragma unroll
  for (int ii = 0; ii < 4; ++ii)
#pragma unroll
    for (int j = 0; j < 4; ++j) acc[ii][j] = (f32x4){0.f, 0.f, 0.f, 0.f};

  const bf16_t* A = P + ((size_t)b * TT + m0) * TT;
  const bf16_t* B = vt + ((size_t)b * CC + n0) * TT;
  gemm_core(A, TT, B, TT, (ti + 1) * 4, smem, smem + 4096, smem + 8192,
            smem + 12288, acc);

  float* Ob = out + (size_t)b * TT * CC;
  float* lds = (float*)smem;  // [64][128] f32, 4-f32-group XOR by row&7
  int tid = threadIdx.x;
  int l = tid & 63, w = tid >> 6;
  int wr = (w >> 1) * 64, wc = (w & 1) * 64;
  (void)wr;
#pragma unroll
  for (int h = 0; h < 2; ++h) {
    __syncthreads();
    if ((w >> 1) == h) {  // waves owning rows [h*64, h*64+64)
#pragma unroll
      for (int mi = 0; mi < 4; ++mi) {
#pragma unroll
        for (int ni = 0; ni < 4; ++ni) {
          int cl = wc + ni * 16 + (l & 15);
          int rb = mi * 16 + (l >> 4) * 4;  // 64-local row base
#pragma unroll
          for (int r = 0; r < 4; ++r) {
            int row = rb + r;
            lds[row * 128 + ((((cl >> 2) ^ (row & 7)) << 2) | (cl & 3))] =
                acc[mi][ni][r];
          }
        }
      }
    }
    __syncthreads();
#pragma unroll
    for (int g = 0; g < 8; ++g) {
      int row = g * 8 + (tid >> 5);  // 0..63
      int c = tid & 31;              // 16B chunk id
      uint4 v =
          *(const uint4*)(lds + row * 128 + ((c ^ (row & 7)) << 2));
      *(uint4*)(Ob + (size_t)(m0 + h * 64 + row) * CC + n0 + c * 4) = v;
    }
  }
}

// ---------------------------------------------------------------------------
extern "C" void kernel_launch(void* const* d_in, const int* in_sizes, int n_in,
                              void* d_out, int out_size, void* d_ws,
                              size_t ws_size, hipStream_t stream) {
  const float* x = (const float*)d_in[0];
  const float* Wq = (const float*)d_in[1];
  const float* bq = (const float*)d_in[2];
  const float* Wk = (const float*)d_in[3];
  const float* bk = (const float*)d_in[4];
  const float* Wv = (const float*)d_in[5];
  const float* bv = (const float*)d_in[6];
  float* out = (float*)d_out;

  char* ws = (char*)d_ws;
  size_t off = 0;
  auto carve = [&](size_t bytes) -> char* {
    char* p = ws + off;
    off += (bytes + 255) & ~(size_t)255;
    return p;
  };
  const size_t M = (size_t)BB * TT;  // 8192
  bf16_t* xbf = (bf16_t*)carve(M * CC * 2);            // 12.6 MB
  bf16_t* wt  = (bf16_t*)carve(3ull * CC * CC * 2);    // 3.5 MB
  bf16_t* qb  = (bf16_t*)carve(M * CC * 2);            // 12.6 MB
  bf16_t* kb  = (bf16_t*)carve(M * CC * 2);            // 12.6 MB
  bf16_t* vt  = (bf16_t*)carve(M * CC * 2);            // 12.6 MB (as [B][H][T])
  _Float16* S = (_Float16*)carve((size_t)BB * TT * TT * 2);  // 33.5 MB
  bf16_t* P   = (bf16_t*)carve((size_t)BB * TT * TT * 2);    // 33.5 MB
  (void)off; (void)ws_size;

  // 1: input prep (cast x + transpose W, one kernel)
  prep_kernel<<<4800, 256, 0, stream>>>(x, Wq, Wk, Wv, xbf, wt);
  // 3: q,k,v
  qkv_gemm_kernel<<<1152, 256, 0, stream>>>(xbf, wt, bq, bk, bv, qb, kb, vt);
  // 4: S = q k^T (lower-tri blocks, fp16)
  s_gemm_kernel<<<544, 256, 0, stream>>>(qb, kb, S);
  // 5: softmax rows -> P (bf16, zero-padded)
  rowstat_kernel<<<BB * TT / 4, 256, 0, stream>>>(S, P);
  // 6: O = P V
  o_gemm_kernel<<<384, 256, 0, stream>>>(P, vt, out);
}